// Round 11
// baseline (93.791 us; speedup 1.0000x reference)
//
#include <hip/hip_runtime.h>
#include <math.h>
#include <stdint.h>

#define LOG2E  1.44269504088896340736f
#define LN2    0.69314718055994530942f
#define LOG2PI 1.8378770664093453f

#define NN 2048
#define DD 64

// Schraudolph (scale 2^16, window [2^23,2^24)): r9-validated, absmax 2.0
#define BIAS_F   16252928.0f
#define KBIT     2205910303u
#define CLAMP_LO 8388608.0f

typedef short  bf16x8 __attribute__((ext_vector_type(8)));
typedef float  f32x16 __attribute__((ext_vector_type(16)));

__device__ __forceinline__ float fexp2(float x) { return __builtin_amdgcn_exp2f(x); }
__device__ __forceinline__ float flog2(float x) { return __builtin_amdgcn_logf(x); }
__device__ __forceinline__ unsigned short f2bf(float f) {
    uint32_t u = __float_as_uint(f);
    u += 0x7FFFu + ((u >> 16) & 1u);   // RNE
    return (unsigned short)(u >> 16);
}

// ---------------------------------------------------------------------------
// K1: factored per-(j,d) params, bf16, transposed [d][*]:
//   -p = 0.5*e^{-lv}*LOG2E ; s' = 256*sqrt(-p) ; ms' = -mean*s'
//   c22s = (-0.5*(lv+LOG2PI)*LOG2E) * 2^16   (bf16: 0.024 log2 quantum, fine)
//   CjS[j] = (sum_d c22 + 64)*2^16 + BIAS_F  (fp32)
//   zT[d][i] = bf16(z)
// blocks 0-31: j-side (64 j x 64 d each); blocks 32-63: i-side (zT).
// ---------------------------------------------------------------------------
__global__ __launch_bounds__(256) void k1(
    const float* __restrict__ z, const float* __restrict__ zm,
    const float* __restrict__ zlv,
    unsigned short* __restrict__ sT, unsigned short* __restrict__ msT,
    unsigned short* __restrict__ c22T, unsigned short* __restrict__ zT,
    float* __restrict__ CjS)
{
    __shared__ float L0[64][65], L1[64][65], L2[64][65];
    int tid = threadIdx.x, lane = tid & 63, row = tid >> 6;
    bool jside = blockIdx.x < 32;
    int rb = (jside ? blockIdx.x : blockIdx.x - 32) * 64;

    if (jside) {
        for (int c = 0; c < 16; ++c) {
            int jl = c * 4 + row;
            int idx = (rb + jl) * DD + lane;       // lane = d
            float mean = zm[idx], lv = zlv[idx];
            float negp = 0.72134752044448170368f * fexp2(-lv * LOG2E);
            float sp   = 256.0f * __builtin_sqrtf(negp);
            float c22  = -0.5f * (lv + LOG2PI) * LOG2E;
            L0[jl][lane] = sp;
            L1[jl][lane] = -mean * sp;
            L2[jl][lane] = c22 * 65536.0f;
            float t = c22;
            #pragma unroll
            for (int off = 32; off; off >>= 1) t += __shfl_xor(t, off, 64);
            if (lane == 0) CjS[rb + jl] = fmaf(t + 64.0f, 65536.0f, BIAS_F);
        }
        __syncthreads();
        for (int c = 0; c < 16; ++c) {
            int dd = c * 4 + row;                  // lane = j
            sT  [dd * NN + rb + lane] = f2bf(L0[lane][dd]);
            msT [dd * NN + rb + lane] = f2bf(L1[lane][dd]);
            c22T[dd * NN + rb + lane] = f2bf(L2[lane][dd]);
        }
    } else {
        for (int c = 0; c < 16; ++c) {
            int il = c * 4 + row;
            L0[il][lane] = z[(rb + il) * DD + lane];
        }
        __syncthreads();
        for (int c = 0; c < 16; ++c) {
            int dd = c * 4 + row;
            zT[dd * NN + rb + lane] = f2bf(L0[lane][dd]);
        }
    }
}

// ---------------------------------------------------------------------------
// KF: fused pass. Wave owns a 32j x 32i tile, loops d=0..63.
// Per d: w'[j,i] = z*s' + 1*ms' via mfma_f32_32x32x16_bf16 (K=2 of 16; k-slot
// mapping invariant: data in lanes 0-31 slots 0-1 of BOTH A and B).
// C/D layout (m74/m101): col=lane&31, row=(reg&3)+8*(reg>>2)+4*(lane>>5).
//  K3 path: E = exp2s(-w'^2 + c22s + BIAS); sum 16 regs + xor32 -> sacc[i,d].
//  K2 path: wsq[reg] += w'^2 across d; epilogue E2 = exp2s(CjS - wsq),
//           sum regs + xor32 -> k2part[jtg*4+w][i].
// Block: 4 waves = 4 j-tiles (128 j); grid 64 it x 16 jtg = 1024.
// LDS: c22 slice 16KB + sacc half-buffer 16KB (d split in 2 flushes).
// ---------------------------------------------------------------------------
__global__ __launch_bounds__(256) void kf(
    const unsigned short* __restrict__ sT, const unsigned short* __restrict__ msT,
    const unsigned short* __restrict__ c22T, const unsigned short* __restrict__ zT,
    const float* __restrict__ CjS,
    float* __restrict__ sums, float* __restrict__ k2part)
{
    __shared__ unsigned short c22L[64 * 128];
    __shared__ float saccL[4][32][32];
    int tid = threadIdx.x, lane = tid & 63, w = tid >> 6;
    int it = blockIdx.x >> 4, jtg = blockIdx.x & 15;
    int i0 = it * 32, jb = jtg * 128;

    for (int k = 0; k < 32; ++k) {               // stage c22 slice [64d][128j]
        int e = k * 256 + tid;
        c22L[e] = c22T[(e >> 7) * NN + jb + (e & 127)];
    }

    int h   = lane >> 5;
    int l31 = lane & 31;
    int jg  = jb + w * 32 + l31;                 // A-row j (lanes 0-31 carry data)
    int ig  = i0 + l31;                          // B-col i
    int jl2 = (w * 32 + 4 * h);                  // c22L ushort base within d-row

    f32x16 zacc;
    float  wsq[16];
    #pragma unroll
    for (int r = 0; r < 16; ++r) { zacc[r] = 0.0f; wsq[r] = 0.0f; }

    __syncthreads();

    for (int half = 0; half < 2; ++half) {
        for (int dl = 0; dl < 32; ++dl) {
            int d = half * 32 + dl;
            unsigned short sv = sT [d * NN + jg];
            unsigned short mv = msT[d * NN + jg];
            unsigned short zv = zT [d * NN + ig];
            uint32_t a0 = (uint32_t)sv | ((uint32_t)mv << 16);
            uint32_t b0 = (uint32_t)zv | 0x3F800000u;    // [z, 1.0bf16]
            if (lane >= 32) { a0 = 0u; b0 = 0u; }
            union { uint4 u; bf16x8 v; } A, B;
            A.u = make_uint4(a0, 0u, 0u, 0u);
            B.u = make_uint4(b0, 0u, 0u, 0u);
            f32x16 acc = __builtin_amdgcn_mfma_f32_32x32x16_bf16(A.v, B.v, zacc, 0, 0, 0);

            const unsigned short* crow = &c22L[d * 128 + jl2];
            float c22f[16];
            #pragma unroll
            for (int rp = 0; rp < 8; ++rp) {
                int Rb = ((2 * rp) & 3) + 8 * ((2 * rp) >> 2);   // even, row-pair base
                uint32_t u = *(const uint32_t*)(crow + Rb);
                c22f[2 * rp]     = __uint_as_float(u << 16);
                c22f[2 * rp + 1] = __uint_as_float(u & 0xFFFF0000u);
            }

            float E[16];
            #pragma unroll
            for (int r = 0; r < 16; ++r) {
                float wv = acc[r];
                float t  = fmaf(wv, -wv, BIAS_F);            // -w'^2 + BIAS
                t += c22f[r];                                 // + c22*2^16
                wsq[r] = fmaf(wv, wv, wsq[r]);                // K2 accumulate
                t = fmaxf(t, CLAMP_LO);
                E[r] = __uint_as_float((__float_as_uint(t) << 7) + KBIT);
            }
            float s0 = (E[0] + E[1])   + (E[2] + E[3]);
            float s1 = (E[4] + E[5])   + (E[6] + E[7]);
            float s2 = (E[8] + E[9])   + (E[10] + E[11]);
            float s3 = (E[12] + E[13]) + (E[14] + E[15]);
            float tot = (s0 + s1) + (s2 + s3);
            tot += __shfl_xor(tot, 32, 64);                   // merge row halves
            if (lane < 32) saccL[w][dl][l31] = tot;
        }
        __syncthreads();
        // block-merge 4 waves' j-partials, flush this d-half
        for (int k = 0; k < 4; ++k) {
            int e = k * 256 + tid;
            int il = e >> 5, dl = e & 31;
            float v = saccL[0][dl][il] + saccL[1][dl][il]
                    + saccL[2][dl][il] + saccL[3][dl][il];
            sums[((size_t)jtg * NN + i0 + il) * DD + half * 32 + dl] = v;
        }
        __syncthreads();
    }

    // K2 epilogue: b2-scaled = CjS - wsq ; Schraudolph; sum over 32 j's
    float cj[16];
    #pragma unroll
    for (int r = 0; r < 16; ++r) {
        int R = (r & 3) + 8 * (r >> 2) + 4 * h;
        cj[r] = CjS[jb + w * 32 + R];
    }
    float E2[16];
    #pragma unroll
    for (int r = 0; r < 16; ++r) {
        float t2 = cj[r] - wsq[r];
        t2 = fmaxf(t2, CLAMP_LO);
        E2[r] = __uint_as_float((__float_as_uint(t2) << 7) + KBIT);
    }
    float q0 = (E2[0] + E2[1])   + (E2[2] + E2[3]);
    float q1 = (E2[4] + E2[5])   + (E2[6] + E2[7]);
    float q2 = (E2[8] + E2[9])   + (E2[10] + E2[11]);
    float q3 = (E2[12] + E2[13]) + (E2[14] + E2[15]);
    float tot2 = (q0 + q1) + (q2 + q3);
    tot2 += __shfl_xor(tot2, 32, 64);
    if (lane < 32) k2part[(size_t)(jtg * 4 + w) * NN + i0 + l31] = tot2;
}

// ---------------------------------------------------------------------------
// K5: diff[i] = LN2*sum_d log2(sum_{16} sums) - LN2*(log2(sum_{64} k2part)-64)
// Wave per i (lane = d for sums; lane = slice for k2part). Grid 512 x 4 i.
// ---------------------------------------------------------------------------
__global__ __launch_bounds__(256) void k5(
    const float* __restrict__ sums, const float* __restrict__ k2part,
    float* __restrict__ diff)
{
    int lane = threadIdx.x & 63, w = threadIdx.x >> 6;
    int i = blockIdx.x * 4 + w;

    float tot = 0.0f;
    #pragma unroll
    for (int g = 0; g < 16; ++g) tot += sums[((size_t)g * NN + i) * DD + lane];
    float t = flog2(tot);
    #pragma unroll
    for (int off = 32; off; off >>= 1) t += __shfl_xor(t, off, 64);

    float s2 = k2part[(size_t)lane * NN + i];
    #pragma unroll
    for (int off = 32; off; off >>= 1) s2 += __shfl_xor(s2, off, 64);

    if (lane == 0) diff[i] = LN2 * t - LN2 * (flog2(s2) - 64.0f);
}

// ---------------------------------------------------------------------------
// K6: out = mean_i diff[i]
// ---------------------------------------------------------------------------
__global__ __launch_bounds__(256) void k6(
    const float* __restrict__ diff, float* __restrict__ out)
{
    __shared__ float red[256];
    int tid = threadIdx.x;
    float t = 0.0f;
    for (int k = tid; k < NN; k += 256) t += diff[k];
    red[tid] = t;
    __syncthreads();
    #pragma unroll
    for (int off = 128; off; off >>= 1) {
        if (tid < off) red[tid] += red[tid + off];
        __syncthreads();
    }
    if (tid == 0) out[0] = red[0] * (1.0f / (float)NN);
}

extern "C" void kernel_launch(void* const* d_in, const int* in_sizes, int n_in,
                              void* d_out, int out_size, void* d_ws, size_t ws_size,
                              hipStream_t stream)
{
    const float* z   = (const float*)d_in[0];
    const float* zm  = (const float*)d_in[1];
    const float* zlv = (const float*)d_in[2];
    float* out = (float*)d_out;

    char* base = (char*)d_ws;
    unsigned short* sT   = (unsigned short*)(base);
    unsigned short* msT  = (unsigned short*)(base + 256 * 1024);
    unsigned short* c22T = (unsigned short*)(base + 512 * 1024);
    unsigned short* zT   = (unsigned short*)(base + 768 * 1024);
    float* CjS  = (float*)(base + 1024 * 1024);                    // 8 KB
    float* sums = (float*)(base + 1024 * 1024 + 8 * 1024);         // 8 MB
    float* k2p  = sums + (size_t)16 * NN * DD;                     // 512 KB
    float* diff = k2p + (size_t)64 * NN;                           // 8 KB

    k1<<<64,   256, 0, stream>>>(z, zm, zlv, sT, msT, c22T, zT, CjS);
    kf<<<1024, 256, 0, stream>>>(sT, msT, c22T, zT, CjS, sums, k2p);
    k5<<<NN / 4, 256, 0, stream>>>(sums, k2p, diff);
    k6<<<1,    256, 0, stream>>>(diff, out);
}

// Round 15
// 61.127 us; speedup vs baseline: 1.5344x; 1.5344x over previous
//
#include <hip/hip_runtime.h>
#include <hip/hip_fp16.h>
#include <math.h>
#include <stdint.h>

#define LOG2E  1.44269504088896340736f
#define LN2    0.69314718055994530942f
#define LOG2PI 1.8378770664093453f

#define NN 2048
#define DD 64

// f32 Schraudolph (validated r8-r10, absmax 2.0): scale 2^16, window [2^23,2^24)
#define BIAS_F   16252928.0f
#define KBIT     2205910303u
#define CLAMP_LO 8388608.0f     // window bottom (x = -120)
#define CLAMP_HI 16777215.0f    // window top    (x = +8)  -> E <= 2^8, finite

// f16 Schraudolph: y = 32*(arg+7) + 1728 in window [1250,2048);
// bits_out = (bits(y)<<5) + KK16 per u16 lane  (= 32y - 39972, in [28, 25532])
#define C1250H 0x64E264E2u   // f16 1250 dup (clamp floor)
#define KK16   0x63DC63DCu   // (-39972) mod 65536, dup'd
#define SHL5   0x00050005u   // per-lane shift amount in a VGPR (NOT inline const)

typedef short          bf16x8 __attribute__((ext_vector_type(8)));
typedef float          f32x16 __attribute__((ext_vector_type(16)));

union PkU { uint32_t u; __half h[2]; };

__device__ __forceinline__ float fexp2(float x) { return __builtin_amdgcn_exp2f(x); }
__device__ __forceinline__ float flog2(float x) { return __builtin_amdgcn_logf(x); }
__device__ __forceinline__ unsigned short f2bf(float f) {
    uint32_t u = __float_as_uint(f);
    u += 0x7FFFu + ((u >> 16) & 1u);   // RNE
    return (unsigned short)(u >> 16);
}
__device__ __forceinline__ float ubf(unsigned short s) {
    return __uint_as_float((uint32_t)s << 16);
}
__device__ __forceinline__ uint32_t bfpack(float a, float b) {
    return (uint32_t)f2bf(a) | ((uint32_t)f2bf(b) << 16);
}
__device__ __forceinline__ uint32_t h1(float x) {
    return (uint32_t)__half_as_ushort(__float2half_rn(x));
}
__device__ __forceinline__ uint32_t hdup(float x) { uint32_t t = h1(x); return t | (t << 16); }
__device__ __forceinline__ uint32_t hpack(float a, float b) { return h1(a) | (h1(b) << 16); }

// packed-f16 primitives via raw asm; ALL operands in VGPRs (no inline-const
// op_sel ambiguity — r13/r14's NaN came from `v_pk_lshlrev_b16 dst, 5, src`).
__device__ __forceinline__ uint32_t pk_fma(uint32_t a, uint32_t b, uint32_t c) {
    uint32_t d;
    asm("v_pk_fma_f16 %0, %1, %2, %3" : "=v"(d) : "v"(a), "v"(b), "v"(c));
    return d;
}
__device__ __forceinline__ uint32_t pk_nfma(uint32_t a, uint32_t b, uint32_t c) {
    uint32_t d;   // d = -a*b + c
    asm("v_pk_fma_f16 %0, %1, %2, %3 neg_lo:[1,0,0] neg_hi:[1,0,0]"
        : "=v"(d) : "v"(a), "v"(b), "v"(c));
    return d;
}
__device__ __forceinline__ uint32_t pk_max(uint32_t a, uint32_t b) {
    uint32_t d;
    asm("v_pk_max_f16 %0, %1, %2" : "=v"(d) : "v"(a), "v"(b));
    return d;
}
__device__ __forceinline__ uint32_t pk_addf(uint32_t a, uint32_t b) {
    uint32_t d;
    asm("v_pk_add_f16 %0, %1, %2" : "=v"(d) : "v"(a), "v"(b));
    return d;
}
__device__ __forceinline__ uint32_t pk_shl(uint32_t a, uint32_t sh) {
    uint32_t d;   // per-u16-lane: a.half << sh.half  (sh in VGPR!)
    asm("v_pk_lshlrev_b16 %0, %1, %2" : "=v"(d) : "v"(sh), "v"(a));
    return d;
}
__device__ __forceinline__ uint32_t pk_addu(uint32_t a, uint32_t b) {
    uint32_t d;   // per-u16-lane add, no cross-lane carry
    asm("v_pk_add_u16 %0, %1, %2" : "=v"(d) : "v"(a), "v"(b));
    return d;
}

// ---------------------------------------------------------------------------
// K1. Per-(j,d) params.
//  f16 K3 form: w' = z*s' + ms', y = C' - w'^2 = 32*arg + 1952;
//     s' = sqrt(32*0.5*log2e)*e^{-lv/2}, ms' = -mu*s', C' = 32*c22 + 1952.
//  K2 split-GEMM features (bf16 hi/lo): p = -0.5*log2e*e^{-lv}, q = -2*mu*p;
//     CjS[j] = (sum_d(mu^2 p + c22) + 64)*65536 + BIAS_F.
//  zpkT[itile][d][u]: f16 i-pairs of z for K3.
// ---------------------------------------------------------------------------
__global__ __launch_bounds__(256) void k1(
    const float* __restrict__ z, const float* __restrict__ zm,
    const float* __restrict__ zlv,
    uint2* __restrict__ smC, uint32_t* __restrict__ Cdup,
    uint32_t* __restrict__ pqfH, uint32_t* __restrict__ pqfL,
    uint32_t* __restrict__ zfH, uint32_t* __restrict__ zfL,
    float* __restrict__ CjS, uint32_t* __restrict__ zpkT)
{
    __shared__ float L[64][65];
    int tid = threadIdx.x, lane = tid & 63, row = tid >> 6;

    if (blockIdx.x < 32) {          // ---- j-side ----
        int jb = blockIdx.x * 64;
        for (int c = 0; c < 16; ++c) {
            int j   = jb + c * 4 + row;
            int idx = j * DD + lane;
            float mean = zm[idx], lv = zlv[idx];
            float p   = -0.72134752f * fexp2(-lv * LOG2E);
            float q   = -2.0f * mean * p;
            float c22 = -0.72134752f * (lv + LOG2PI);
            float sp  = 5.65685424f * __builtin_sqrtf(-p);
            float msp = -mean * sp;
            float Cp  = fmaf(32.0f, c22, 1952.0f);
            smC[idx]  = make_uint2(hdup(sp), hdup(msp));
            Cdup[idx] = hdup(Cp);
            unsigned short hp = f2bf(p), hq = f2bf(q);
            pqfH[idx] = (uint32_t)hp | ((uint32_t)hq << 16);
            pqfL[idx] = bfpack(p - ubf(hp), q - ubf(hq));
            float t = fmaf(mean * mean, p, c22);
            #pragma unroll
            for (int off = 32; off; off >>= 1) t += __shfl_xor(t, off, 64);
            if (lane == 0) CjS[j] = fmaf(t + 64.0f, 65536.0f, BIAS_F);
        }
    } else {                        // ---- i-side ----
        int ib = (blockIdx.x - 32) * 64;
        for (int c = 0; c < 16; ++c) {
            int il  = c * 4 + row;
            int idx = (ib + il) * DD + lane;
            float zv = z[idx];
            L[il][lane] = zv;
            float z2 = zv * zv;
            unsigned short hz2 = f2bf(z2), hz = f2bf(zv);
            zfH[idx] = (uint32_t)hz2 | ((uint32_t)hz << 16);
            zfL[idx] = bfpack(z2 - ubf(hz2), zv - ubf(hz));
        }
        __syncthreads();
        for (int k = 0; k < 8; ++k) {
            int e = k * 256 + tid;
            int u = e & 7, d = (e >> 3) & 63, itl = e >> 9;
            float za = L[itl * 16 + 2 * u][d];
            float zb = L[itl * 16 + 2 * u + 1][d];
            zpkT[((ib >> 4) + itl) * 512 + d * 8 + u] = hpack(za, zb);
        }
    }
}

// ---------------------------------------------------------------------------
// K3. sums[jsl][i][d] = (sum_{j in 256-slice} 2^{arg+7}) * 2^-4, f16 out.
// Packed-f16 Schraudolph: 6 pk-insts / 2 elems, zero trans ops, all-VGPR asm.
// Window safe: arg <= c22max ~ 2.2 -> y <= ~2022 < 2048; clamp floor 1250.
// Acc bound: 64 terms x <=~580 = ~37k < 65504 (no f16 overflow).
// Block 256 = 4 waves (16-i tile, 4 j-subslices of 64); lane = d.
// Grid: 128 itiles x 8 jslices = 1024.
// ---------------------------------------------------------------------------
__global__ __launch_bounds__(256) void k3(
    const uint2* __restrict__ smC, const uint32_t* __restrict__ Cdup,
    const uint32_t* __restrict__ zpkT, __half* __restrict__ sums)
{
    __shared__ float sm[4][16][64];
    int tid = threadIdx.x, lane = tid & 63, w = tid >> 6;
    int it = blockIdx.x >> 3, jsl = blockIdx.x & 7;
    int j0 = jsl * 256 + w * 64;

    uint32_t zpk[8], acc[8];
    #pragma unroll
    for (int u = 0; u < 8; ++u) {
        zpk[u] = zpkT[it * 512 + lane * 8 + u];
        acc[u] = 0u;
    }

    // force the packed constants into VGPRs once
    uint32_t kk = KK16, sh5 = SHL5, clf = C1250H;
    asm volatile("" : "+v"(kk), "+v"(sh5), "+v"(clf));

    const uint2*    sp = smC  + (size_t)j0 * DD + lane;
    const uint32_t* cp = Cdup + (size_t)j0 * DD + lane;

    #pragma unroll 4
    for (int jj = 0; jj < 64; ++jj) {
        uint2    sv = sp[(size_t)jj * DD];
        uint32_t Cv = cp[(size_t)jj * DD];
        #pragma unroll
        for (int u = 0; u < 8; ++u) {
            uint32_t wp = pk_fma(zpk[u], sv.x, sv.y);      // w' = z*s' + ms'
            uint32_t y  = pk_nfma(wp, wp, Cv);             // y  = C' - w'^2
            y = pk_max(y, clf);                             // clamp to window
            uint32_t e = pk_addu(pk_shl(y, sh5), kk);       // Schraudolph bits
            acc[u] = pk_addf(acc[u], e);                    // f16x2 accumulate
        }
    }

    #pragma unroll
    for (int u = 0; u < 8; ++u) {
        PkU a; a.u = acc[u];
        sm[w][2 * u][lane]     = __half2float(a.h[0]);
        sm[w][2 * u + 1][lane] = __half2float(a.h[1]);
    }
    __syncthreads();
    #pragma unroll
    for (int k = 0; k < 4; ++k) {
        int e = k * 256 + tid;
        int il = e >> 6, d = e & 63;
        float v = sm[0][il][d] + sm[1][il][d] + sm[2][il][d] + sm[3][il][d];
        sums[((size_t)jsl * NN + it * 16 + il) * DD + d] =
            __float2half_rn(v * 0.0625f);
    }
}

// ---------------------------------------------------------------------------
// K2. log_qz inner sums via SPLIT bf16 MFMA GEMM:
//   b2[j,i] = sum_k pq[j,k]*zz[i,k]; b2 ~= AH.BH + AH.BL + AL.BH.
//   Epilogue: f32 Schraudolph with BOTH clamps (NaN-proof).
// Wave = (i-tile 32, 2 j-tiles). Grid 512 x 256 (2048 waves).
// ---------------------------------------------------------------------------
__global__ __launch_bounds__(256) void k2(
    const uint32_t* __restrict__ zfH, const uint32_t* __restrict__ zfL,
    const uint32_t* __restrict__ pqfH, const uint32_t* __restrict__ pqfL,
    const float* __restrict__ CjS, float* __restrict__ k2part)
{
    __shared__ float cjsL[NN];
    int tid = threadIdx.x, lane = tid & 63, w = tid >> 6;
    for (int t = tid; t < NN; t += 256) cjsL[t] = CjS[t];
    __syncthreads();

    int gid = blockIdx.x * 4 + w;       // 0..2047
    int it = gid >> 5, jg = gid & 31;
    int l31 = lane & 31, h = lane >> 5;

    const char* zbH = (const char*)zfH + (size_t)(it * 32 + l31) * 256 + h * 16;
    const char* zbL = (const char*)zfL + (size_t)(it * 32 + l31) * 256 + h * 16;
    bf16x8 BH[8], BL[8];
    #pragma unroll
    for (int kc = 0; kc < 8; ++kc) {
        BH[kc] = *(const bf16x8*)(zbH + kc * 32);
        BL[kc] = *(const bf16x8*)(zbL + kc * 32);
    }

    float isum = 0.0f;
    #pragma unroll
    for (int t4 = 0; t4 < 2; ++t4) {
        int jt = jg * 2 + t4;
        const char* abH = (const char*)pqfH + (size_t)(jt * 32 + l31) * 256 + h * 16;
        const char* abL = (const char*)pqfL + (size_t)(jt * 32 + l31) * 256 + h * 16;
        f32x16 acc;
        #pragma unroll
        for (int r = 0; r < 16; ++r) acc[r] = 0.0f;
        #pragma unroll
        for (int kc = 0; kc < 8; ++kc) {
            bf16x8 AH = *(const bf16x8*)(abH + kc * 32);
            bf16x8 AL = *(const bf16x8*)(abL + kc * 32);
            acc = __builtin_amdgcn_mfma_f32_32x32x16_bf16(AH, BH[kc], acc, 0, 0, 0);
            acc = __builtin_amdgcn_mfma_f32_32x32x16_bf16(AH, BL[kc], acc, 0, 0, 0);
            acc = __builtin_amdgcn_mfma_f32_32x32x16_bf16(AL, BH[kc], acc, 0, 0, 0);
        }
        #pragma unroll
        for (int r = 0; r < 16; ++r) {
            int R = (r & 3) + 8 * (r >> 2) + 4 * h;
            float y = fmaf(acc[r], 65536.0f, cjsL[jt * 32 + R]);
            y = fminf(fmaxf(y, CLAMP_LO), CLAMP_HI);
            isum += __uint_as_float((__float_as_uint(y) << 7) + KBIT);
        }
    }
    isum += __shfl_xor(isum, 32, 64);
    if (lane < 32) k2part[(size_t)jg * NN + it * 32 + l31] = isum;
}

// ---------------------------------------------------------------------------
// K5. diff[i] = LN2*( sum_d log2(sum_{8} sums) - log2(sum_{32} k2part) - 128 )
//  (K3: +7/d and 2^-4 store scale -> +448-256 = +192; K2: +64; net 128.)
// ---------------------------------------------------------------------------
__global__ __launch_bounds__(256) void k5(
    const __half* __restrict__ sums, const float* __restrict__ k2part,
    float* __restrict__ diff)
{
    int lane = threadIdx.x & 63, w = threadIdx.x >> 6;
    int i = blockIdx.x * 4 + w;

    float tot = 0.0f;
    #pragma unroll
    for (int q = 0; q < 8; ++q)
        tot += __half2float(sums[((size_t)q * NN + i) * DD + lane]);
    float t = flog2(tot);
    #pragma unroll
    for (int off = 32; off; off >>= 1) t += __shfl_xor(t, off, 64);

    float s2 = (lane < 32) ? k2part[(size_t)lane * NN + i] : 0.0f;
    #pragma unroll
    for (int off = 32; off; off >>= 1) s2 += __shfl_xor(s2, off, 64);

    if (lane == 0) diff[i] = LN2 * (t - flog2(s2) - 128.0f);
}

// ---------------------------------------------------------------------------
// K6: out = mean_i diff[i]
// ---------------------------------------------------------------------------
__global__ __launch_bounds__(256) void k6(
    const float* __restrict__ diff, float* __restrict__ out)
{
    __shared__ float red[256];
    int tid = threadIdx.x;
    float t = 0.0f;
    for (int k = tid; k < NN; k += 256) t += diff[k];
    red[tid] = t;
    __syncthreads();
    #pragma unroll
    for (int off = 128; off; off >>= 1) {
        if (tid < off) red[tid] += red[tid + off];
        __syncthreads();
    }
    if (tid == 0) out[0] = red[0] * (1.0f / (float)NN);
}

extern "C" void kernel_launch(void* const* d_in, const int* in_sizes, int n_in,
                              void* d_out, int out_size, void* d_ws, size_t ws_size,
                              hipStream_t stream)
{
    const float* z   = (const float*)d_in[0];
    const float* zm  = (const float*)d_in[1];
    const float* zlv = (const float*)d_in[2];
    float* out = (float*)d_out;

    char* b = (char*)d_ws;
    uint2*    smC  = (uint2*)(b);                               // 1 MB
    uint32_t* Cdup = (uint32_t*)(b + (1 << 20));                // 512 KB
    uint32_t* zpkT = (uint32_t*)(b + (1 << 20) + (512 << 10));  // 256 KB
    uint32_t* pqfH = (uint32_t*)(b + (1 << 20) + (768 << 10));  // 512 KB
    uint32_t* pqfL = (uint32_t*)(b + (2 << 20) + (256 << 10));  // 512 KB
    uint32_t* zfH  = (uint32_t*)(b + (2 << 20) + (768 << 10));  // 512 KB
    uint32_t* zfL  = (uint32_t*)(b + (3 << 20) + (256 << 10));  // 512 KB
    float*    CjS  = (float*)(b + (3 << 20) + (768 << 10));     // 8 KB
    __half*   sums = (__half*)(b + (4 << 20));                  // 2 MB
    float*    k2p  = (float*)(b + (6 << 20));                   // 256 KB
    float*    diff = (float*)(b + (6 << 20) + (256 << 10));     // 8 KB

    k1<<<64,   256, 0, stream>>>(z, zm, zlv, smC, Cdup, pqfH, pqfL, zfH, zfL, CjS, zpkT);
    k3<<<1024, 256, 0, stream>>>(smC, Cdup, zpkT, sums);
    k2<<<512,  256, 0, stream>>>(zfH, zfL, pqfH, pqfL, CjS, k2p);
    k5<<<512,  256, 0, stream>>>(sums, k2p, diff);
    k6<<<1,    256, 0, stream>>>(diff, out);
}

// Round 16
// 47.785 us; speedup vs baseline: 1.9628x; 1.2792x over previous
//
#include <hip/hip_runtime.h>
#include <hip/hip_fp16.h>
#include <math.h>
#include <stdint.h>

#define LOG2E  1.44269504088896340736f
#define LN2    0.69314718055994530942f
#define LOG2PI 1.8378770664093453f

#define NN 2048
#define DD 64

// f32 Schraudolph (validated r8-r15): scale 2^16, window [2^23,2^24)
#define BIAS_F   16252928.0f
#define KBIT     2205910303u
#define CLAMP_LO 8388608.0f
#define CLAMP_HI 16777215.0f

// f16 Schraudolph (validated r15): y = 32*(arg+7)+1728 in [1250,2048)
#define C1250H 0x64E264E2u
#define KK16   0x63DC63DCu
#define SHL5   0x00050005u

typedef short          bf16x8 __attribute__((ext_vector_type(8)));
typedef float          f32x16 __attribute__((ext_vector_type(16)));

union PkU { uint32_t u; __half h[2]; };

__device__ __forceinline__ float fexp2(float x) { return __builtin_amdgcn_exp2f(x); }
__device__ __forceinline__ float flog2(float x) { return __builtin_amdgcn_logf(x); }
__device__ __forceinline__ unsigned short f2bf(float f) {
    uint32_t u = __float_as_uint(f);
    u += 0x7FFFu + ((u >> 16) & 1u);
    return (unsigned short)(u >> 16);
}
__device__ __forceinline__ float ubf(unsigned short s) {
    return __uint_as_float((uint32_t)s << 16);
}
__device__ __forceinline__ uint32_t bfpack(float a, float b) {
    return (uint32_t)f2bf(a) | ((uint32_t)f2bf(b) << 16);
}
__device__ __forceinline__ uint32_t h1(float x) {
    return (uint32_t)__half_as_ushort(__float2half_rn(x));
}
__device__ __forceinline__ uint32_t hdup(float x) { uint32_t t = h1(x); return t | (t << 16); }
__device__ __forceinline__ uint32_t hpack(float a, float b) { return h1(a) | (h1(b) << 16); }

// packed-f16 primitives, all operands in VGPRs (r14's NaN = inline-const op_sel)
__device__ __forceinline__ uint32_t pk_fma(uint32_t a, uint32_t b, uint32_t c) {
    uint32_t d;
    asm("v_pk_fma_f16 %0, %1, %2, %3" : "=v"(d) : "v"(a), "v"(b), "v"(c));
    return d;
}
__device__ __forceinline__ uint32_t pk_nfma(uint32_t a, uint32_t b, uint32_t c) {
    uint32_t d;
    asm("v_pk_fma_f16 %0, %1, %2, %3 neg_lo:[1,0,0] neg_hi:[1,0,0]"
        : "=v"(d) : "v"(a), "v"(b), "v"(c));
    return d;
}
__device__ __forceinline__ uint32_t pk_max(uint32_t a, uint32_t b) {
    uint32_t d;
    asm("v_pk_max_f16 %0, %1, %2" : "=v"(d) : "v"(a), "v"(b));
    return d;
}
__device__ __forceinline__ uint32_t pk_addf(uint32_t a, uint32_t b) {
    uint32_t d;
    asm("v_pk_add_f16 %0, %1, %2" : "=v"(d) : "v"(a), "v"(b));
    return d;
}
__device__ __forceinline__ uint32_t pk_shl(uint32_t a, uint32_t sh) {
    uint32_t d;
    asm("v_pk_lshlrev_b16 %0, %1, %2" : "=v"(d) : "v"(sh), "v"(a));
    return d;
}
__device__ __forceinline__ uint32_t pk_addu(uint32_t a, uint32_t b) {
    uint32_t d;
    asm("v_pk_add_u16 %0, %1, %2" : "=v"(d) : "v"(a), "v"(b));
    return d;
}

// ---------------------------------------------------------------------------
// K1. Per-(j,d) params (3x parallelism vs r15: 192 blocks).
// blocks [0,128): j-side, 16 rows each. blocks [128,192): i-side, 32 rows.
//  smC4[j*64+d] = {s'dup, ms'dup, C'dup, 0} (f16-dup packed, single ldx4)
//  pqfH/L[j][2d] = bf16 hi/lo {p,q}; zfH/L[i][2d] = bf16 hi/lo {z^2,z}
//  CjS[j] = (sum_d(mu^2 p + c22)+64)*65536 + BIAS_F; zpkT = f16 i-pairs of z.
// ---------------------------------------------------------------------------
__global__ __launch_bounds__(256) void k1(
    const float* __restrict__ z, const float* __restrict__ zm,
    const float* __restrict__ zlv,
    uint4* __restrict__ smC4,
    uint32_t* __restrict__ pqfH, uint32_t* __restrict__ pqfL,
    uint32_t* __restrict__ zfH, uint32_t* __restrict__ zfL,
    float* __restrict__ CjS, uint32_t* __restrict__ zpkT)
{
    __shared__ float L[32][65];
    int tid = threadIdx.x, lane = tid & 63, row = tid >> 6;

    if (blockIdx.x < 128) {         // ---- j-side: 16 rows ----
        int jb = blockIdx.x * 16;
        #pragma unroll
        for (int c = 0; c < 4; ++c) {
            int j   = jb + c * 4 + row;
            int idx = j * DD + lane;
            float mean = zm[idx], lv = zlv[idx];
            float p   = -0.72134752f * fexp2(-lv * LOG2E);
            float q   = -2.0f * mean * p;
            float c22 = -0.72134752f * (lv + LOG2PI);
            float sp  = 5.65685424f * __builtin_sqrtf(-p);
            float msp = -mean * sp;
            float Cp  = fmaf(32.0f, c22, 1952.0f);
            smC4[idx] = make_uint4(hdup(sp), hdup(msp), hdup(Cp), 0u);
            unsigned short hp = f2bf(p), hq = f2bf(q);
            pqfH[idx] = (uint32_t)hp | ((uint32_t)hq << 16);
            pqfL[idx] = bfpack(p - ubf(hp), q - ubf(hq));
            float t = fmaf(mean * mean, p, c22);
            #pragma unroll
            for (int off = 32; off; off >>= 1) t += __shfl_xor(t, off, 64);
            if (lane == 0) CjS[j] = fmaf(t + 64.0f, 65536.0f, BIAS_F);
        }
    } else {                        // ---- i-side: 32 rows ----
        int ib = (blockIdx.x - 128) * 32;
        #pragma unroll
        for (int c = 0; c < 8; ++c) {
            int il  = c * 4 + row;
            int idx = (ib + il) * DD + lane;
            float zv = z[idx];
            L[il][lane] = zv;
            float z2 = zv * zv;
            unsigned short hz2 = f2bf(z2), hz = f2bf(zv);
            zfH[idx] = (uint32_t)hz2 | ((uint32_t)hz << 16);
            zfL[idx] = bfpack(z2 - ubf(hz2), zv - ubf(hz));
        }
        __syncthreads();
        #pragma unroll
        for (int k = 0; k < 4; ++k) {      // 2 local 16-i tiles x 64 d x 8 u
            int e = k * 256 + tid;
            int u = e & 7, d = (e >> 3) & 63, itl = e >> 9;
            float za = L[itl * 16 + 2 * u][d];
            float zb = L[itl * 16 + 2 * u + 1][d];
            zpkT[((ib >> 4) + itl) * 512 + d * 8 + u] = hpack(za, zb);
        }
    }
}

// ---------------------------------------------------------------------------
// KW. Merged k3+k2 (MFMA waves overlap VALU waves across blocks, m114).
// blocks [0,1024): K3 — sums[jsl][i][d] = (sum_{256-slice j} 2^{arg+7})*2^-4,
//   f16-Schraudolph pipeline, 6 pk-insts / 2 elems, single uint4 load per jj.
// blocks [1024,1536): K2 — split bf16 MFMA GEMM (AH.BH+AH.BL+AL.BH) +
//   dual-clamped f32 Schraudolph epilogue (NaN-proof), r15-validated.
// ---------------------------------------------------------------------------
__global__ __launch_bounds__(256) void kw(
    const uint4* __restrict__ smC4, const uint32_t* __restrict__ zpkT,
    const uint32_t* __restrict__ zfH, const uint32_t* __restrict__ zfL,
    const uint32_t* __restrict__ pqfH, const uint32_t* __restrict__ pqfL,
    const float* __restrict__ CjS,
    __half* __restrict__ sums, float* __restrict__ k2part)
{
    __shared__ float shbuf[4096];   // 16 KB, shared by both paths
    int tid = threadIdx.x, lane = tid & 63, w = tid >> 6;

    if (blockIdx.x < 1024) {
        // ================= K3 path =================
        float (*sm)[16][64] = (float (*)[16][64])shbuf;
        int it = blockIdx.x >> 3, jsl = blockIdx.x & 7;
        int j0 = jsl * 256 + w * 64;

        uint32_t zpk[8], acc[8];
        #pragma unroll
        for (int u = 0; u < 8; ++u) {
            zpk[u] = zpkT[it * 512 + lane * 8 + u];
            acc[u] = 0u;
        }
        uint32_t kk = KK16, sh5 = SHL5, clf = C1250H;
        asm volatile("" : "+v"(kk), "+v"(sh5), "+v"(clf));

        const uint4* sp = smC4 + (size_t)j0 * DD + lane;
        #pragma unroll 4
        for (int jj = 0; jj < 64; ++jj) {
            uint4 v = sp[(size_t)jj * DD];   // {s', ms', C', -}
            #pragma unroll
            for (int u = 0; u < 8; ++u) {
                uint32_t wp = pk_fma(zpk[u], v.x, v.y);   // w' = z*s' + ms'
                uint32_t y  = pk_nfma(wp, wp, v.z);       // y  = C' - w'^2
                y = pk_max(y, clf);
                uint32_t e = pk_addu(pk_shl(y, sh5), kk);
                acc[u] = pk_addf(acc[u], e);
            }
        }

        #pragma unroll
        for (int u = 0; u < 8; ++u) {
            PkU a; a.u = acc[u];
            sm[w][2 * u][lane]     = __half2float(a.h[0]);
            sm[w][2 * u + 1][lane] = __half2float(a.h[1]);
        }
        __syncthreads();
        #pragma unroll
        for (int k = 0; k < 4; ++k) {
            int e = k * 256 + tid;
            int il = e >> 6, d = e & 63;
            float v2 = sm[0][il][d] + sm[1][il][d] + sm[2][il][d] + sm[3][il][d];
            sums[((size_t)jsl * NN + it * 16 + il) * DD + d] =
                __float2half_rn(v2 * 0.0625f);
        }
    } else {
        // ================= K2 path =================
        float* cjsL = shbuf;
        for (int t = tid; t < NN; t += 256) cjsL[t] = CjS[t];
        __syncthreads();

        int gid = (blockIdx.x - 1024) * 4 + w;   // 0..2047
        int it = gid >> 5, jg = gid & 31;
        int l31 = lane & 31, h = lane >> 5;

        const char* zbH = (const char*)zfH + (size_t)(it * 32 + l31) * 256 + h * 16;
        const char* zbL = (const char*)zfL + (size_t)(it * 32 + l31) * 256 + h * 16;
        bf16x8 BH[8], BL[8];
        #pragma unroll
        for (int kc = 0; kc < 8; ++kc) {
            BH[kc] = *(const bf16x8*)(zbH + kc * 32);
            BL[kc] = *(const bf16x8*)(zbL + kc * 32);
        }

        float isum = 0.0f;
        #pragma unroll
        for (int t4 = 0; t4 < 2; ++t4) {
            int jt = jg * 2 + t4;
            const char* abH = (const char*)pqfH + (size_t)(jt * 32 + l31) * 256 + h * 16;
            const char* abL = (const char*)pqfL + (size_t)(jt * 32 + l31) * 256 + h * 16;
            f32x16 acc;
            #pragma unroll
            for (int r = 0; r < 16; ++r) acc[r] = 0.0f;
            #pragma unroll
            for (int kc = 0; kc < 8; ++kc) {
                bf16x8 AH = *(const bf16x8*)(abH + kc * 32);
                bf16x8 AL = *(const bf16x8*)(abL + kc * 32);
                acc = __builtin_amdgcn_mfma_f32_32x32x16_bf16(AH, BH[kc], acc, 0, 0, 0);
                acc = __builtin_amdgcn_mfma_f32_32x32x16_bf16(AH, BL[kc], acc, 0, 0, 0);
                acc = __builtin_amdgcn_mfma_f32_32x32x16_bf16(AL, BH[kc], acc, 0, 0, 0);
            }
            #pragma unroll
            for (int r = 0; r < 16; ++r) {
                int R = (r & 3) + 8 * (r >> 2) + 4 * h;
                float y = fmaf(acc[r], 65536.0f, cjsL[jt * 32 + R]);
                y = fminf(fmaxf(y, CLAMP_LO), CLAMP_HI);
                isum += __uint_as_float((__float_as_uint(y) << 7) + KBIT);
            }
        }
        isum += __shfl_xor(isum, 32, 64);
        if (lane < 32) k2part[(size_t)jg * NN + it * 32 + l31] = isum;
    }
}

// ---------------------------------------------------------------------------
// K5. diff[i] = LN2*( sum_d log2(sum_{8} sums) - log2(sum_{32} k2part) - 128 )
// ---------------------------------------------------------------------------
__global__ __launch_bounds__(256) void k5(
    const __half* __restrict__ sums, const float* __restrict__ k2part,
    float* __restrict__ diff)
{
    int lane = threadIdx.x & 63, w = threadIdx.x >> 6;
    int i = blockIdx.x * 4 + w;

    float tot = 0.0f;
    #pragma unroll
    for (int q = 0; q < 8; ++q)
        tot += __half2float(sums[((size_t)q * NN + i) * DD + lane]);
    float t = flog2(tot);
    #pragma unroll
    for (int off = 32; off; off >>= 1) t += __shfl_xor(t, off, 64);

    float s2 = (lane < 32) ? k2part[(size_t)lane * NN + i] : 0.0f;
    #pragma unroll
    for (int off = 32; off; off >>= 1) s2 += __shfl_xor(s2, off, 64);

    if (lane == 0) diff[i] = LN2 * (t - flog2(s2) - 128.0f);
}

// ---------------------------------------------------------------------------
// K6: out = mean_i diff[i]
// ---------------------------------------------------------------------------
__global__ __launch_bounds__(256) void k6(
    const float* __restrict__ diff, float* __restrict__ out)
{
    __shared__ float red[256];
    int tid = threadIdx.x;
    float t = 0.0f;
    for (int k = tid; k < NN; k += 256) t += diff[k];
    red[tid] = t;
    __syncthreads();
    #pragma unroll
    for (int off = 128; off; off >>= 1) {
        if (tid < off) red[tid] += red[tid + off];
        __syncthreads();
    }
    if (tid == 0) out[0] = red[0] * (1.0f / (float)NN);
}

extern "C" void kernel_launch(void* const* d_in, const int* in_sizes, int n_in,
                              void* d_out, int out_size, void* d_ws, size_t ws_size,
                              hipStream_t stream)
{
    const float* z   = (const float*)d_in[0];
    const float* zm  = (const float*)d_in[1];
    const float* zlv = (const float*)d_in[2];
    float* out = (float*)d_out;

    char* b = (char*)d_ws;
    uint4*    smC4 = (uint4*)(b);                               // 2 MB
    uint32_t* pqfH = (uint32_t*)(b + (2 << 20));                // 512 KB
    uint32_t* pqfL = (uint32_t*)(b + (2 << 20) + (512 << 10));  // 512 KB
    uint32_t* zfH  = (uint32_t*)(b + (3 << 20));                // 512 KB
    uint32_t* zfL  = (uint32_t*)(b + (3 << 20) + (512 << 10));  // 512 KB
    uint32_t* zpkT = (uint32_t*)(b + (4 << 20));                // 256 KB
    float*    CjS  = (float*)(b + (4 << 20) + (256 << 10));     // 8 KB
    __half*   sums = (__half*)(b + (5 << 20));                  // 2 MB
    float*    k2p  = (float*)(b + (7 << 20));                   // 256 KB
    float*    diff = (float*)(b + (7 << 20) + (256 << 10));     // 8 KB

    k1<<<192,  256, 0, stream>>>(z, zm, zlv, smC4, pqfH, pqfL, zfH, zfL, CjS, zpkT);
    kw<<<1536, 256, 0, stream>>>(smC4, zpkT, zfH, zfL, pqfH, pqfL, CjS, sums, k2p);
    k5<<<512,  256, 0, stream>>>(sums, k2p, diff);
    k6<<<1,    256, 0, stream>>>(diff, out);
}